// Round 4
// baseline (562.638 us; speedup 1.0000x reference)
//
#include <hip/hip_runtime.h>
#include <hip/hip_bf16.h>

typedef __attribute__((ext_vector_type(8))) short short8;
typedef __attribute__((ext_vector_type(4))) short short4_t;
typedef __attribute__((ext_vector_type(4))) float floatx4;
typedef __attribute__((ext_vector_type(16))) float floatx16;

#define MFMA_B16(a,b,c) __builtin_amdgcn_mfma_f32_16x16x32_bf16((a),(b),(c),0,0,0)
#define MFMA32(a,b,c)   __builtin_amdgcn_mfma_f32_32x32x16_bf16((a),(b),(c),0,0,0)

__device__ __forceinline__ short f2bf(float f) {
    union { __hip_bfloat16 h; short s; } u;
    u.h = __float2bfloat16(f);
    return u.s;
}

union S8U { short4_t h[2]; short8 v; };

// ---------------- problem constants ----------------
#define N_FRAMES 4096
#define C_IN     9
#define POS      121
#define NF       64
#define FC_K     7744     // k = p*64 + c
#define ISTR     20       // conv0 input LDS stride (elems)
#define FSZ      10816    // 169*64 elems per frame LDS image

// ---------------- workspace offsets (bytes) ----------------
#define OFF_W0    0                       // [9][2][32][16] bf16 (18432 B)
#define OFF_WP    18432                   // [7][9][2][4][32][2][8] bf16 (516096 B)
#define OFF_FCP   534528                  // [64][7744] bf16, k=p*64+c (991232 B)
#define OFF_WIHT  1525760                 // [64][256] f32 (65536 B)
#define OFF_BSUM  1591296                 // [256] f32 (1024 B)
#define OFF_ACTS  1592320                 // [4096][7744] bf16 (63438848 B)
#define OFF_XG    66079744                // [4096][256] f32 (4194304 B)
#define OFF_HOUT  70274048                // [4096][64] f32 (1048576 B)  end=71322624

// ================= prep: pack conv weights, w_ih^T, biases =================
// Weights packed for 32x32x16 MFMA.
//   conv0:  w0 [tap9][mt2][o32][ci16]  (ci 9..15 zero-padded)
//   conv1-7: wpk [l][tap][mt2][ks4][o32][kh2][e8], ci = ks*16 + kh*8 + e
// Lane l&31 = out-channel row o, l>>5 = kh (k-half). A and B use the SAME
// channel->k mapping, so correctness is independent of the HW k-permutation.
__global__ __launch_bounds__(256) void prep_kernel(
    const float* __restrict__ conv0_w, const float* __restrict__ conv_ws,
    const float* __restrict__ w_ih,
    const float* __restrict__ b_ih, const float* __restrict__ b_hh,
    short* __restrict__ w0, short* __restrict__ wpk,
    float* __restrict__ wihT, float* __restrict__ bsum)
{
    int idx = blockIdx.x*256 + threadIdx.x;
    if (idx < 9216) {  // conv0: [tap][mt][o][ci16]
        int tap = idx >> 10; int r = idx & 1023;
        int mt = r >> 9; int o = (r >> 4) & 31; int ci = r & 15;
        int oc = mt*32 + o;
        float v = (ci < 9) ? conv0_w[(oc*9 + ci)*9 + tap] : 0.f;
        w0[idx] = f2bf(v);
        return;
    }
    idx -= 9216;
    if (idx < 258048) {  // conv1-7: [l][tap][mt][ks][o][kh][e]
        int l = idx / 36864; int r = idx % 36864;
        int tap = r >> 12; int rr = r & 4095;
        int mt = rr >> 11;
        int ks = (rr >> 9) & 3;
        int o  = (rr >> 4) & 31;
        int ci16 = rr & 15;               // kh*8 + e
        int oc = mt*32 + o;
        int ci = ks*16 + ci16;
        wpk[idx] = f2bf(conv_ws[((l*64 + oc)*64 + ci)*9 + tap]);
        return;
    }
    idx -= 258048;
    if (idx < 16384) {  // w_ih^T: [k][g]
        int k = idx >> 8; int g = idx & 255;
        wihT[idx] = w_ih[g*64 + k];
        return;
    }
    idx -= 16384;
    if (idx < 256) bsum[idx] = b_ih[idx] + b_hh[idx];
}

// ================= fc weight transpose: [u][c*121+p] f32 -> [u][p*64+c] bf16 =====
__global__ __launch_bounds__(256) void fc_transpose(
    const float* __restrict__ fc_w, short* __restrict__ fcp)
{
    __shared__ float row[FC_K];          // 30976 B
    const int u = blockIdx.x;
    const int tid = threadIdx.x;
    const float* src = fc_w + (size_t)u*FC_K;
    for (int i = tid; i < FC_K; i += 256) row[i] = src[i];
    __syncthreads();
    short* dst = fcp + (size_t)u*FC_K;
    for (int k2 = tid; k2 < FC_K; k2 += 256) {
        int p = k2 >> 6, c = k2 & 63;
        dst[k2] = f2bf(row[c*121 + p]);
    }
}

// ========== fused 8-layer conv stack: R16 = R14 + ks-granular 4-deep pipeline ==========
// R16 theory: R14's VGPR_Count=60 proved the compiler allocated ~no load
// buffers -> every load->MFMA pair serialized on ~250cyc L2/LDS latency
// (per-wave stall ~1500cyc/layer, MfmaUtil pinned 43%). R15's full-tap
// double-buffer (128 VGPR) overflowed the scheduler's pressure heuristic
// AND lost occupancy via (128,2). Fix: 4-slot rotating buffer at ks
// granularity (64 VGPR): micro-step = {4 MFMAs of slot s from tap t-1;
// refill slot s from tap t}. Consume distance = 4 slots ~ 240cyc, covers
// L2 (~200) + LDS (~150). Total regs ~165 -> 3 waves/SIMD with (128,3):
// pipeline AND occupancy together this time.
// Swizzled act layout (unchanged): cell (Y,X) of 13x13 grid, 64 ch in 8
// groups of 8 bf16; group G at slot ((G + 11*Y + X + 4) & 7).
//   interior cell of logical p: slot = (G + p) & 7
//   tap cell (base + dy,dx):    slot = (G + p + 11*dy + dx + 4) & 7
// p = 32*nt + n (n=lane&31) => p mod 8 = n mod 8, slot uniform across nt.

#define SLOAD(t_,ks_,AA,AB,BA,BB) { \
    const short* wt_ = wl + (t_)*4096; \
    const int so_ = (((t_)/3)*13 + ((t_)%3))*128 \
                  + (((((t_)/3)*11 + ((t_)%3) + 4 + kh + n + 2*(ks_)) & 7) << 4); \
    AA = *(const short8*)(wt_ + (ks_)*512); \
    AB = *(const short8*)(wt_ + 2048 + (ks_)*512); \
    BA = *(const short8*)(actb + vbase[0] + so_); \
    BB = *(const short8*)(actb + vbase[1] + so_); }

#define SMFMA(AA,AB,BA,BB) { \
    acc[0][0] = MFMA32(AA, BA, acc[0][0]); \
    acc[1][0] = MFMA32(AB, BA, acc[1][0]); \
    acc[0][1] = MFMA32(AA, BB, acc[0][1]); \
    acc[1][1] = MFMA32(AB, BB, acc[1][1]); }

__global__ __launch_bounds__(128, 3) void conv_stack(
    const float* __restrict__ x,
    const float* __restrict__ conv0_b,
    const float* __restrict__ conv_bs,
    const short* __restrict__ w0,
    const short* __restrict__ wpk,
    short* __restrict__ acts_out)
{
    __shared__ alignas(16) short act[FSZ];   // 21632 B, shared by 2 waves
    const int tid  = threadIdx.x;
    const int lane = tid & 63;
    const int wv   = tid >> 6;     // wave 0/1: owns nt = wv*2 + {0,1}
    const int n    = lane & 31;    // N col / A row (out-channel) index
    const int kh   = lane >> 5;    // k-half: channels kh*8 .. kh*8+7 of each 16
    char* actb = (char*)act;

    const short8 zero8 = {0,0,0,0,0,0,0,0};
    const floatx16 fz16 = {};

    // zero conv0 staging region (13*13*20 = 3380, pad 3392), split 128 thr
    for (int i = tid*8; i < 3392; i += 1024) *(short8*)(&act[i]) = zero8;
    __syncthreads();

    // stage input frame fp32 -> bf16 ([Y][X][ci] stride 20; x is [ci][y][x])
    {
        const float* xf = x + (size_t)blockIdx.x*(C_IN*POS);
        for (int i = tid; i < C_IN*POS; i += 128) {
            int ci = i / POS;
            int p  = i - ci*POS;
            int yy = p / 11;
            int xx = p - yy*11;
            act[((yy+1)*13 + (xx+1))*ISTR + ci] = f2bf(xf[i]);
        }
    }
    __syncthreads();

    floatx16 acc[2][2];    // [mt][local nt]
    #pragma unroll
    for (int mt=0;mt<2;mt++)
        #pragma unroll
        for (int j=0;j<2;j++) acc[mt][j] = fz16;

    // per-local-nt tap-base cell (clamped); vbase = byte base in swizzled layout
    int cell20[2], vbase[2], wbase[2];
    #pragma unroll
    for (int j = 0; j < 2; ++j) {
        int p = (wv*2 + j)*32 + n;
        int pc = (p <= 120) ? p : 120;
        int yy = pc / 11, xx = pc - yy*11;
        int cell = yy*13 + xx;
        cell20[j] = cell*ISTR;
        vbase[j]  = cell*128;
        wbase[j]  = (cell + 14)*128;    // interior cell (+1,+1)
    }
    const bool tail = (wv == 1) && (n > 24);   // p > 120 on local j==1

    // ---- conv0 (K real 9, padded to 16; pad is zero in both A and B) ----
    {
        const short* w0l = w0 + n*16 + kh*8;
        #pragma unroll 1
        for (int dy = 0; dy < 3; ++dy) {
            #pragma unroll 1
            for (int dx = 0; dx < 3; ++dx) {
                const short* wt = w0l + (dy*3+dx)*1024;
                short8 a0 = *(const short8*)(wt);
                short8 a1 = *(const short8*)(wt + 512);
                const int so = (dy*13+dx)*ISTR + kh*8;
                #pragma unroll
                for (int j=0;j<2;j++) {
                    const short* bp = act + cell20[j] + so;
                    S8U t;
                    t.h[0] = *(const short4_t*)(bp);
                    t.h[1] = *(const short4_t*)(bp + 4);
                    acc[0][j] = MFMA32(a0, t.v, acc[0][j]);
                    acc[1][j] = MFMA32(a1, t.v, acc[1][j]);
                }
            }
        }
    }

    // conv0 input dead; zero the full swizzled act buffer (halo must be 0)
    __syncthreads();                      // both waves done reading staging
    for (int i = tid*8; i < FSZ; i += 1024) *(short8*)(&act[i]) = zero8;

    // epilogue: bias+relu+bf16 -> swizzled act interior (wave writes its 2 nt)
    // C/D layout 32x32 (HW-verified): col = lane&31 = position,
    // row = (r&3) + 8*(r>>2) + 4*kh  => r = q*4+jj holds ch mt*32 + q*8 + kh*4 + jj
    auto epilogue = [&](const float* bias) {
        __syncthreads();                  // all reads (or zeroing) complete
        #pragma unroll
        for (int mt=0;mt<2;mt++) {
            #pragma unroll
            for (int q=0;q<4;q++) {
                const int ch0 = mt*32 + q*8 + kh*4;
                const floatx4 bb = *(const floatx4*)(bias + ch0);
                // G = mt*4+q; slot = (G+p)&7, p mod 8 = n mod 8 -> uniform in nt
                const int soff = (((mt*4 + q + n) & 7) << 4) + kh*8;
                #pragma unroll
                for (int j=0;j<2;j++) {
                    if (j == 1 && tail) continue;   // p > 120
                    short4_t sv;
                    sv.x = f2bf(fmaxf(acc[mt][j][q*4+0] + bb.x, 0.f));
                    sv.y = f2bf(fmaxf(acc[mt][j][q*4+1] + bb.y, 0.f));
                    sv.z = f2bf(fmaxf(acc[mt][j][q*4+2] + bb.z, 0.f));
                    sv.w = f2bf(fmaxf(acc[mt][j][q*4+3] + bb.w, 0.f));
                    *(short4_t*)(actb + wbase[j] + soff) = sv;
                }
            }
        }
        #pragma unroll
        for (int mt=0;mt<2;mt++)
            #pragma unroll
            for (int j=0;j<2;j++) acc[mt][j] = fz16;
        __syncthreads();                  // writes visible before next reads
    };

    epilogue(conv0_b);

    // ---- conv layers 1..7: ks-granular 4-slot rotating pipeline (R16) ----
    {
        short8 a00,a01,b00,b01;   // slot 0
        short8 a10,a11,b10,b11;   // slot 1
        short8 a20,a21,b20,b21;   // slot 2
        short8 a30,a31,b30,b31;   // slot 3
        #pragma unroll 1
        for (int l = 1; l < 8; ++l) {
            const short* wl = wpk + (l-1)*36864 + n*16 + kh*8;
            // prologue: fill all 4 slots from tap 0
            SLOAD(0,0,a00,a01,b00,b01);
            SLOAD(0,1,a10,a11,b10,b11);
            SLOAD(0,2,a20,a21,b20,b21);
            SLOAD(0,3,a30,a31,b30,b31);
            // taps 1..8: consume slot s (tap t-1), refill slot s (tap t)
            #pragma unroll
            for (int t = 1; t < 9; ++t) {
                SMFMA(a00,a01,b00,b01); SLOAD(t,0,a00,a01,b00,b01);
                SMFMA(a10,a11,b10,b11); SLOAD(t,1,a10,a11,b10,b11);
                SMFMA(a20,a21,b20,b21); SLOAD(t,2,a20,a21,b20,b21);
                SMFMA(a30,a31,b30,b31); SLOAD(t,3,a30,a31,b30,b31);
            }
            // drain tap 8
            SMFMA(a00,a01,b00,b01);
            SMFMA(a10,a11,b10,b11);
            SMFMA(a20,a21,b20,b21);
            SMFMA(a30,a31,b30,b31);
            epilogue(conv_bs + (l-1)*NF);
        }
    }

    // final copy: acts[f][p*64 + c], un-swizzled, coalesced 16B global writes
    {
        short* dst = acts_out + (size_t)blockIdx.x*FC_K;
        #pragma unroll 1
        for (int it = 0; it < 8; ++it) {
            int q = it*128 + tid;
            if (q < 968) {                    // 121 pos * 8 ch-groups
                int p = q >> 3, G = q & 7;
                int yy = p / 11, xx = p - yy*11;
                int cell = (yy+1)*13 + (xx+1);
                int slot = (G + p) & 7;
                short8 v = *(const short8*)(actb + cell*128 + slot*16);
                *(short8*)(dst + q*8) = v;
            }
        }
    }
}

// ===== fused FC + xg: xg[f][g] = relu(acts[f]@fcp^T + fc_b) @ wihT + bsum =====
__global__ __launch_bounds__(256) void fc_xg_kernel(
    const short* __restrict__ acts, const short* __restrict__ fcp,
    const float* __restrict__ fc_b, const float* __restrict__ wihT,
    const float* __restrict__ bsum, float* __restrict__ xg)
{
    __shared__ alignas(16) float red[3*64*16];   // 12288 B
    __shared__ alignas(16) float fbuf[16*64];    // 4096 B
    const int tid  = threadIdx.x;
    const int lane = tid & 63;
    const int w    = tid >> 6;
    const int m    = lane & 15;
    const int kg   = lane >> 4;
    const int bm   = blockIdx.x;     // 256 blocks x 16 frames

    const floatx4 fzero = {0.f,0.f,0.f,0.f};
    floatx4 acc[4];
    #pragma unroll
    for (int nt=0;nt<4;nt++) acc[nt] = fzero;

    const short* arow = acts + (size_t)(bm*16 + m)*FC_K + kg*8;
    const short* brow = fcp + (size_t)m*FC_K + kg*8;

    for (int kc = w; kc < 242; kc += 4) {   // K split across 4 waves
        short8 a = *(const short8*)(arow + kc*32);
        #pragma unroll
        for (int nt=0;nt<4;nt++) {
            short8 b = *(const short8*)(brow + (size_t)nt*16*FC_K + kc*32);
            acc[nt] = MFMA_B16(a, b, acc[nt]);
        }
    }

    if (w > 0) {
        #pragma unroll
        for (int nt=0;nt<4;nt++)
            *(floatx4*)(&red[((w-1)*64 + lane)*16 + nt*4]) = acc[nt];
    }
    __syncthreads();
    if (w == 0) {
        #pragma unroll
        for (int nt=0;nt<4;nt++)
            for (int j=0;j<3;j++)
                acc[nt] += *(const floatx4*)(&red[(j*64 + lane)*16 + nt*4]);
        #pragma unroll
        for (int nt=0;nt<4;nt++) {
            int unit = nt*16 + m;
            float bias = fc_b[unit];
            int fr = kg*4;                    // local frame 0..15
            fbuf[(fr+0)*NF + unit] = fmaxf(acc[nt].x + bias, 0.f);
            fbuf[(fr+1)*NF + unit] = fmaxf(acc[nt].y + bias, 0.f);
            fbuf[(fr+2)*NF + unit] = fmaxf(acc[nt].z + bias, 0.f);
            fbuf[(fr+3)*NF + unit] = fmaxf(acc[nt].w + bias, 0.f);
        }
    }
    __syncthreads();

    // xg phase: thread g computes 16 frames x 1 gate
    {
        const int g = tid;
        float a[16];
        float bs = bsum[g];
        #pragma unroll
        for (int i=0;i<16;i++) a[i] = bs;
        for (int k=0;k<64;k++) {
            float wk = wihT[k*256 + g];
            #pragma unroll
            for (int i=0;i<16;i++) a[i] += fbuf[i*64 + k] * wk;
        }
        float* xo = xg + (size_t)(bm*16)*256 + g;
        #pragma unroll
        for (int i=0;i<16;i++) xo[i*256] = a[i];
    }
}

// ================= LSTM recurrence =================
// fast sigmoid/tanh: __expf + hw rcp; saturate correctly at +/-inf
// (validated R10/R11: absmax unchanged at 2.441e-4)
__device__ __forceinline__ float sigmf_(float v){
    return __builtin_amdgcn_rcpf(1.f + __expf(-v));
}
__device__ __forceinline__ float tanhf_(float v){
    return 1.f - 2.f*__builtin_amdgcn_rcpf(__expf(2.f*v) + 1.f);
}

__global__ __launch_bounds__(128) void lstm_kernel(
    const float* __restrict__ xg, const float* __restrict__ whh,
    float* __restrict__ hout)
{
    __shared__ alignas(16) float hbuf[64];
    __shared__ alignas(16) float gbuf[256];
    const int t = threadIdx.x;
    const int b = blockIdx.x;

    float4 w0v[16], w1v[16];
    #pragma unroll
    for (int k=0;k<16;k++) w0v[k] = *(const float4*)(whh + t*64 + k*4);
    #pragma unroll
    for (int k=0;k<16;k++) w1v[k] = *(const float4*)(whh + (t+128)*64 + k*4);

    float c = 0.f;
    if (t < 64) hbuf[t] = 0.f;
    __syncthreads();

    const float* xr = xg + (size_t)(b*128)*256;
    float nA = xr[t];
    float nB = xr[t+128];

    for (int ts=0; ts<128; ++ts) {
        float aA = nA, aB = nB;
        if (ts + 1 < 128) {
            const float* xn = xr + (ts+1)*256;
            nA = xn[t];
            nB = xn[t+128];
        }
        #pragma unroll
        for (int k=0;k<16;k++) {
            float4 hv = *(const float4*)(&hbuf[k*4]);
            aA += hv.x*w0v[k].x + hv.y*w0v[k].y + hv.z*w0v[k].z + hv.w*w0v[k].w;
            aB += hv.x*w1v[k].x + hv.y*w1v[k].y + hv.z*w1v[k].z + hv.w*w1v[k].w;
        }
        gbuf[t] = aA;
        gbuf[t+128] = aB;
        __syncthreads();
        if (t < 64) {   // gate order i,f,g,o
            float ig = sigmf_(gbuf[t]);
            float fg = sigmf_(gbuf[64+t]);
            float gg = tanhf_(gbuf[128+t]);
            float og = sigmf_(gbuf[192+t]);
            c = fg*c + ig*gg;
            float h = og*tanhf_(c);
            hbuf[t] = h;
            hout[(b*128+ts)*64 + t] = h;
        }
        __syncthreads();
    }
}

// ================= policy/value heads (fp32) =================
__global__ __launch_bounds__(64) void heads_kernel(
    const float* __restrict__ hout,
    const float* __restrict__ p1w, const float* __restrict__ p1b,
    const float* __restrict__ p2w, const float* __restrict__ p2b,
    const float* __restrict__ v1w, const float* __restrict__ v1b,
    const float* __restrict__ v2w, const float* __restrict__ v2b,
    float* __restrict__ out)
{
    __shared__ alignas(16) float hbuf[64];
    __shared__ alignas(16) float a1[128];
    __shared__ alignas(16) float a2[128];
    const int lane = threadIdx.x;
    for (int fi=0; fi<4; ++fi) {
        const int f = blockIdx.x*4 + fi;
        hbuf[lane] = hout[f*64 + lane];
        __syncthreads();
        #pragma unroll
        for (int uu=0; uu<2; ++uu) {
            const int u = lane + uu*64;
            float s1 = p1b[u], s2 = v1b[u];
            const float4* wp1 = (const float4*)(p1w + u*64);
            const float4* wv1 = (const float4*)(v1w + u*64);
            #pragma unroll
            for (int k=0;k<16;k++) {
                float4 h4 = *(const float4*)(&hbuf[k*4]);
                float4 w4 = wp1[k];
                s1 += h4.x*w4.x + h4.y*w4.y + h4.z*w4.z + h4.w*w4.w;
                float4 q4 = wv1[k];
                s2 += h4.x*q4.x + h4.y*q4.y + h4.z*q4.z + h4.w*q4.w;
            }
            a1[u] = fmaxf(s1, 0.f);
            a2[u] = fmaxf(s2, 0.f);
        }
        __syncthreads();
        if (lane < 6) {
            float s = p2b[lane];
            const float* wr = p2w + lane*128;
            #pragma unroll
            for (int j=0;j<128;j++) s += a1[j]*wr[j];
            out[f*6 + lane] = s;
        }
        if (lane == 6) {
            float s = v2b[0];
            #pragma unroll
            for (int j=0;j<128;j++) s += a2[j]*v2w[j];
            out[24576 + f] = s;
        }
        __syncthreads();
    }
}

extern "C" void kernel_launch(void* const* d_in, const int* in_sizes, int n_in,
                              void* d_out, int out_size, void* d_ws, size_t ws_size,
                              hipStream_t stream) {
    const float* x       = (const float*)d_in[0];
    const float* conv0_w = (const float*)d_in[1];
    const float* conv0_b = (const float*)d_in[2];
    const float* conv_ws = (const float*)d_in[3];
    const float* conv_bs = (const float*)d_in[4];
    const float* fc_w    = (const float*)d_in[5];
    const float* fc_b    = (const float*)d_in[6];
    const float* w_ih    = (const float*)d_in[7];
    const float* w_hh    = (const float*)d_in[8];
    const float* b_ih    = (const float*)d_in[9];
    const float* b_hh    = (const float*)d_in[10];
    const float* p1_w    = (const float*)d_in[11];
    const float* p1_b    = (const float*)d_in[12];
    const float* p2_w    = (const float*)d_in[13];
    const float* p2_b    = (const float*)d_in[14];
    const float* v1_w    = (const float*)d_in[15];
    const float* v1_b    = (const float*)d_in[16];
    const float* v2_w    = (const float*)d_in[17];
    const float* v2_b    = (const float*)d_in[18];
    float* out = (float*)d_out;

    char* ws = (char*)d_ws;
    short* w0    = (short*)(ws + OFF_W0);
    short* wpk   = (short*)(ws + OFF_WP);
    short* fcp   = (short*)(ws + OFF_FCP);
    float* wihT  = (float*)(ws + OFF_WIHT);
    float* bsum  = (float*)(ws + OFF_BSUM);
    short* acts  = (short*)(ws + OFF_ACTS);
    float* xgb   = (float*)(ws + OFF_XG);
    float* hout  = (float*)(ws + OFF_HOUT);

    prep_kernel<<<1109, 256, 0, stream>>>(conv0_w, conv_ws, w_ih, b_ih, b_hh,
                                          w0, wpk, wihT, bsum);
    fc_transpose<<<64, 256, 0, stream>>>(fc_w, fcp);
    conv_stack<<<N_FRAMES, 128, 0, stream>>>(x, conv0_b, conv_bs, w0, wpk, acts);
    fc_xg_kernel<<<256, 256, 0, stream>>>(acts, fcp, fc_b, wihT, bsum, xgb);
    lstm_kernel<<<32, 128, 0, stream>>>(xgb, w_hh, hout);
    heads_kernel<<<1024, 64, 0, stream>>>(hout, p1_w, p1_b, p2_w, p2_b,
                                          v1_w, v1_b, v2_w, v2_b, out);
}

// Round 5
// 505.008 us; speedup vs baseline: 1.1141x; 1.1141x over previous
//
#include <hip/hip_runtime.h>
#include <hip/hip_bf16.h>

typedef __attribute__((ext_vector_type(8))) short short8;
typedef __attribute__((ext_vector_type(4))) short short4_t;
typedef __attribute__((ext_vector_type(4))) float floatx4;
typedef __attribute__((ext_vector_type(16))) float floatx16;

#define MFMA_B16(a,b,c) __builtin_amdgcn_mfma_f32_16x16x32_bf16((a),(b),(c),0,0,0)
#define MFMA32(a,b,c)   __builtin_amdgcn_mfma_f32_32x32x16_bf16((a),(b),(c),0,0,0)

__device__ __forceinline__ short f2bf(float f) {
    union { __hip_bfloat16 h; short s; } u;
    u.h = __float2bfloat16(f);
    return u.s;
}

union S8U { short4_t h[2]; short8 v; };

// ---------------- problem constants ----------------
#define N_FRAMES 4096
#define C_IN     9
#define POS      121
#define NF       64
#define FC_K     7744     // k = p*64 + c
#define ISTR     20       // conv0 input LDS stride (elems)
#define FSZ      10816    // 169*64 elems per frame LDS image

// ---------------- workspace offsets (bytes) ----------------
#define OFF_W0    0                       // [9][2][32][16] bf16 (18432 B)
#define OFF_WP    18432                   // [7][9][2][4][32][2][8] bf16 (516096 B)
#define OFF_FCP   534528                  // [64][7744] bf16, k=p*64+c (991232 B)
#define OFF_WIHT  1525760                 // [64][256] f32 (65536 B)
#define OFF_BSUM  1591296                 // [256] f32 (1024 B)
#define OFF_ACTS  1592320                 // [4096][7744] bf16 (63438848 B)
#define OFF_XG    66079744                // [4096][256] f32 (4194304 B)
#define OFF_HOUT  70274048                // [4096][64] f32 (1048576 B)  end=71322624

// ================= prep: pack conv weights, w_ih^T, biases =================
// Weights packed for 32x32x16 MFMA.
//   conv0:  w0 [tap9][mt2][o32][ci16]  (ci 9..15 zero-padded)
//   conv1-7: wpk [l][tap][mt2][ks4][o32][kh2][e8], ci = ks*16 + kh*8 + e
// Lane l&31 = out-channel row o, l>>5 = kh (k-half). A and B use the SAME
// channel->k mapping, so correctness is independent of the HW k-permutation.
__global__ __launch_bounds__(256) void prep_kernel(
    const float* __restrict__ conv0_w, const float* __restrict__ conv_ws,
    const float* __restrict__ w_ih,
    const float* __restrict__ b_ih, const float* __restrict__ b_hh,
    short* __restrict__ w0, short* __restrict__ wpk,
    float* __restrict__ wihT, float* __restrict__ bsum)
{
    int idx = blockIdx.x*256 + threadIdx.x;
    if (idx < 9216) {  // conv0: [tap][mt][o][ci16]
        int tap = idx >> 10; int r = idx & 1023;
        int mt = r >> 9; int o = (r >> 4) & 31; int ci = r & 15;
        int oc = mt*32 + o;
        float v = (ci < 9) ? conv0_w[(oc*9 + ci)*9 + tap] : 0.f;
        w0[idx] = f2bf(v);
        return;
    }
    idx -= 9216;
    if (idx < 258048) {  // conv1-7: [l][tap][mt][ks][o][kh][e]
        int l = idx / 36864; int r = idx % 36864;
        int tap = r >> 12; int rr = r & 4095;
        int mt = rr >> 11;
        int ks = (rr >> 9) & 3;
        int o  = (rr >> 4) & 31;
        int ci16 = rr & 15;               // kh*8 + e
        int oc = mt*32 + o;
        int ci = ks*16 + ci16;
        wpk[idx] = f2bf(conv_ws[((l*64 + oc)*64 + ci)*9 + tap]);
        return;
    }
    idx -= 258048;
    if (idx < 16384) {  // w_ih^T: [k][g]
        int k = idx >> 8; int g = idx & 255;
        wihT[idx] = w_ih[g*64 + k];
        return;
    }
    idx -= 16384;
    if (idx < 256) bsum[idx] = b_ih[idx] + b_hh[idx];
}

// ================= fc weight transpose: [u][c*121+p] f32 -> [u][p*64+c] bf16 =====
__global__ __launch_bounds__(256) void fc_transpose(
    const float* __restrict__ fc_w, short* __restrict__ fcp)
{
    __shared__ float row[FC_K];          // 30976 B
    const int u = blockIdx.x;
    const int tid = threadIdx.x;
    const float* src = fc_w + (size_t)u*FC_K;
    for (int i = tid; i < FC_K; i += 256) row[i] = src[i];
    __syncthreads();
    short* dst = fcp + (size_t)u*FC_K;
    for (int k2 = tid; k2 < FC_K; k2 += 256) {
        int p = k2 >> 6, c = k2 & 63;
        dst[k2] = f2bf(row[c*121 + p]);
    }
}

// ========== fused 8-layer conv stack: R17 = R14 + fenced A-prefetch pipeline ==========
// R16 post-mortem: VGPR_Count=68 proved the 4-slot rotation was never
// allocated -- the scheduler sank every load to its consumer (as in R15).
// R17 keeps R14's shape (N-split, 2 waves/frame, (128,3)) and enforces the
// pipeline with sched_barrier(0): micro-step i = {4 B ds_reads of i;
// 4 A global loads of i+1; FENCE; 8 MFMAs of i}. Loads cannot sink past
// the fence (>=256 MFMA-pipe cyc ahead of use, covers L2~200); B-reads and
// next-step loads may hoist into the previous MFMA cluster (covers LDS~120).
// Waitcnts become counted (vmcnt(4)) instead of per-pair drains.
// Buffers: AX/AY 16 VGPR each, compile-time alternation -> ~150-165 total
// regs incl 64 acc AGPRs: stays in the 170-reg 3-waves/SIMD bin.
// Swizzled act layout (unchanged): cell (Y,X) of 13x13 grid, 64 ch in 8
// groups of 8 bf16; group G at slot ((G + 11*Y + X + 4) & 7).
//   interior cell of logical p: slot = (G + p) & 7
//   tap cell (base + dy,dx):    slot = (G + p + 11*dy + dx + 4) & 7
// p = 32*nt + n (n=lane&31) => p mod 8 = n mod 8, slot uniform across nt.
__global__ __launch_bounds__(128, 3) void conv_stack(
    const float* __restrict__ x,
    const float* __restrict__ conv0_b,
    const float* __restrict__ conv_bs,
    const short* __restrict__ w0,
    const short* __restrict__ wpk,
    short* __restrict__ acts_out)
{
    __shared__ alignas(16) short act[FSZ];   // 21632 B, shared by 2 waves
    const int tid  = threadIdx.x;
    const int lane = tid & 63;
    const int wv   = tid >> 6;     // wave 0/1: owns nt = wv*2 + {0,1}
    const int n    = lane & 31;    // N col / A row (out-channel) index
    const int kh   = lane >> 5;    // k-half: channels kh*8 .. kh*8+7 of each 16
    char* actb = (char*)act;

    const short8 zero8 = {0,0,0,0,0,0,0,0};
    const floatx16 fz16 = {};

    // zero conv0 staging region (13*13*20 = 3380, pad 3392), split 128 thr
    for (int i = tid*8; i < 3392; i += 1024) *(short8*)(&act[i]) = zero8;
    __syncthreads();

    // stage input frame fp32 -> bf16 ([Y][X][ci] stride 20; x is [ci][y][x])
    {
        const float* xf = x + (size_t)blockIdx.x*(C_IN*POS);
        for (int i = tid; i < C_IN*POS; i += 128) {
            int ci = i / POS;
            int p  = i - ci*POS;
            int yy = p / 11;
            int xx = p - yy*11;
            act[((yy+1)*13 + (xx+1))*ISTR + ci] = f2bf(xf[i]);
        }
    }
    __syncthreads();

    floatx16 acc[2][2];    // [mt][local nt]
    #pragma unroll
    for (int mt=0;mt<2;mt++)
        #pragma unroll
        for (int j=0;j<2;j++) acc[mt][j] = fz16;

    // per-local-nt tap-base cell (clamped); vbase = byte base in swizzled layout
    int cell20[2], vbase[2], wbase[2];
    #pragma unroll
    for (int j = 0; j < 2; ++j) {
        int p = (wv*2 + j)*32 + n;
        int pc = (p <= 120) ? p : 120;
        int yy = pc / 11, xx = pc - yy*11;
        int cell = yy*13 + xx;
        cell20[j] = cell*ISTR;
        vbase[j]  = cell*128;
        wbase[j]  = (cell + 14)*128;    // interior cell (+1,+1)
    }
    const bool tail = (wv == 1) && (n > 24);   // p > 120 on local j==1

    // ---- conv0 (K real 9, padded to 16; pad is zero in both A and B) ----
    {
        const short* w0l = w0 + n*16 + kh*8;
        #pragma unroll 1
        for (int dy = 0; dy < 3; ++dy) {
            #pragma unroll 1
            for (int dx = 0; dx < 3; ++dx) {
                const short* wt = w0l + (dy*3+dx)*1024;
                short8 a0 = *(const short8*)(wt);
                short8 a1 = *(const short8*)(wt + 512);
                const int so = (dy*13+dx)*ISTR + kh*8;
                #pragma unroll
                for (int j=0;j<2;j++) {
                    const short* bp = act + cell20[j] + so;
                    S8U t;
                    t.h[0] = *(const short4_t*)(bp);
                    t.h[1] = *(const short4_t*)(bp + 4);
                    acc[0][j] = MFMA32(a0, t.v, acc[0][j]);
                    acc[1][j] = MFMA32(a1, t.v, acc[1][j]);
                }
            }
        }
    }

    // conv0 input dead; zero the full swizzled act buffer (halo must be 0)
    __syncthreads();                      // both waves done reading staging
    for (int i = tid*8; i < FSZ; i += 1024) *(short8*)(&act[i]) = zero8;

    // epilogue: bias+relu+bf16 -> swizzled act interior (wave writes its 2 nt)
    // C/D layout 32x32 (HW-verified): col = lane&31 = position,
    // row = (r&3) + 8*(r>>2) + 4*kh  => r = q*4+jj holds ch mt*32 + q*8 + kh*4 + jj
    auto epilogue = [&](const float* bias) {
        __syncthreads();                  // all reads (or zeroing) complete
        #pragma unroll
        for (int mt=0;mt<2;mt++) {
            #pragma unroll
            for (int q=0;q<4;q++) {
                const int ch0 = mt*32 + q*8 + kh*4;
                const floatx4 bb = *(const floatx4*)(bias + ch0);
                // G = mt*4+q; slot = (G+p)&7, p mod 8 = n mod 8 -> uniform in nt
                const int soff = (((mt*4 + q + n) & 7) << 4) + kh*8;
                #pragma unroll
                for (int j=0;j<2;j++) {
                    if (j == 1 && tail) continue;   // p > 120
                    short4_t sv;
                    sv.x = f2bf(fmaxf(acc[mt][j][q*4+0] + bb.x, 0.f));
                    sv.y = f2bf(fmaxf(acc[mt][j][q*4+1] + bb.y, 0.f));
                    sv.z = f2bf(fmaxf(acc[mt][j][q*4+2] + bb.z, 0.f));
                    sv.w = f2bf(fmaxf(acc[mt][j][q*4+3] + bb.w, 0.f));
                    *(short4_t*)(actb + wbase[j] + soff) = sv;
                }
            }
        }
        #pragma unroll
        for (int mt=0;mt<2;mt++)
            #pragma unroll
            for (int j=0;j<2;j++) acc[mt][j] = fz16;
        __syncthreads();                  // writes visible before next reads
    };

    epilogue(conv0_b);

    // ---- conv layers 1..7: fenced 1-microstep-ahead A-prefetch (R17) ----
    // micro-step i (0..17): tap tp=i>>1, k-pair kp=i&1 (ks = 2kp, 2kp+1)
    {
        short8 AX0,AX1,AX2,AX3, AY0,AY1,AY2,AY3;
        #pragma unroll 1
        for (int l = 1; l < 8; ++l) {
            const short* wl = wpk + (l-1)*36864 + n*16 + kh*8;
            // prologue: A for micro-step 0 -> AX  (mt0/mt1 of ks 0,1)
            AX0 = *(const short8*)(wl);
            AX1 = *(const short8*)(wl + 2048);
            AX2 = *(const short8*)(wl + 512);
            AX3 = *(const short8*)(wl + 2560);
            #pragma unroll
            for (int i = 0; i < 18; ++i) {
                const int tp = i >> 1, kp = i & 1;
                const int sb_ = ((tp/3)*13 + (tp%3))*128;
                const int cu_ = (tp/3)*11 + (tp%3) + 4 + kh + n + 4*kp;
                const int so0 = sb_ + ((cu_ & 7) << 4);
                const int so1 = sb_ + (((cu_ + 2) & 7) << 4);
                // B reads of step i (may hoist into step i-1's MFMA cluster)
                short8 b00 = *(const short8*)(actb + vbase[0] + so0);
                short8 b01 = *(const short8*)(actb + vbase[1] + so0);
                short8 b10 = *(const short8*)(actb + vbase[0] + so1);
                short8 b11 = *(const short8*)(actb + vbase[1] + so1);
                // A prefetch of step i+1 into the idle buffer
                if (i < 17) {
                    const int j = i + 1;
                    const short* wt_ = wl + (j>>1)*4096 + (j&1)*1024;
                    if ((i & 1) == 0) {
                        AY0 = *(const short8*)(wt_);
                        AY1 = *(const short8*)(wt_ + 2048);
                        AY2 = *(const short8*)(wt_ + 512);
                        AY3 = *(const short8*)(wt_ + 2560);
                    } else {
                        AX0 = *(const short8*)(wt_);
                        AX1 = *(const short8*)(wt_ + 2048);
                        AX2 = *(const short8*)(wt_ + 512);
                        AX3 = *(const short8*)(wt_ + 2560);
                    }
                }
                __builtin_amdgcn_sched_barrier(0);   // loads may not sink below
                if ((i & 1) == 0) {                  // consume AX
                    acc[0][0]=MFMA32(AX0,b00,acc[0][0]); acc[1][0]=MFMA32(AX1,b00,acc[1][0]);
                    acc[0][1]=MFMA32(AX0,b01,acc[0][1]); acc[1][1]=MFMA32(AX1,b01,acc[1][1]);
                    acc[0][0]=MFMA32(AX2,b10,acc[0][0]); acc[1][0]=MFMA32(AX3,b10,acc[1][0]);
                    acc[0][1]=MFMA32(AX2,b11,acc[0][1]); acc[1][1]=MFMA32(AX3,b11,acc[1][1]);
                } else {                             // consume AY
                    acc[0][0]=MFMA32(AY0,b00,acc[0][0]); acc[1][0]=MFMA32(AY1,b00,acc[1][0]);
                    acc[0][1]=MFMA32(AY0,b01,acc[0][1]); acc[1][1]=MFMA32(AY1,b01,acc[1][1]);
                    acc[0][0]=MFMA32(AY2,b10,acc[0][0]); acc[1][0]=MFMA32(AY3,b10,acc[1][0]);
                    acc[0][1]=MFMA32(AY2,b11,acc[0][1]); acc[1][1]=MFMA32(AY3,b11,acc[1][1]);
                }
            }
            epilogue(conv_bs + (l-1)*NF);
        }
    }

    // final copy: acts[f][p*64 + c], un-swizzled, coalesced 16B global writes
    {
        short* dst = acts_out + (size_t)blockIdx.x*FC_K;
        #pragma unroll 1
        for (int it = 0; it < 8; ++it) {
            int q = it*128 + tid;
            if (q < 968) {                    // 121 pos * 8 ch-groups
                int p = q >> 3, G = q & 7;
                int yy = p / 11, xx = p - yy*11;
                int cell = (yy+1)*13 + (xx+1);
                int slot = (G + p) & 7;
                short8 v = *(const short8*)(actb + cell*128 + slot*16);
                *(short8*)(dst + q*8) = v;
            }
        }
    }
}

// ===== fused FC + xg: xg[f][g] = relu(acts[f]@fcp^T + fc_b) @ wihT + bsum =====
__global__ __launch_bounds__(256) void fc_xg_kernel(
    const short* __restrict__ acts, const short* __restrict__ fcp,
    const float* __restrict__ fc_b, const float* __restrict__ wihT,
    const float* __restrict__ bsum, float* __restrict__ xg)
{
    __shared__ alignas(16) float red[3*64*16];   // 12288 B
    __shared__ alignas(16) float fbuf[16*64];    // 4096 B
    const int tid  = threadIdx.x;
    const int lane = tid & 63;
    const int w    = tid >> 6;
    const int m    = lane & 15;
    const int kg   = lane >> 4;
    const int bm   = blockIdx.x;     // 256 blocks x 16 frames

    const floatx4 fzero = {0.f,0.f,0.f,0.f};
    floatx4 acc[4];
    #pragma unroll
    for (int nt=0;nt<4;nt++) acc[nt] = fzero;

    const short* arow = acts + (size_t)(bm*16 + m)*FC_K + kg*8;
    const short* brow = fcp + (size_t)m*FC_K + kg*8;

    for (int kc = w; kc < 242; kc += 4) {   // K split across 4 waves
        short8 a = *(const short8*)(arow + kc*32);
        #pragma unroll
        for (int nt=0;nt<4;nt++) {
            short8 b = *(const short8*)(brow + (size_t)nt*16*FC_K + kc*32);
            acc[nt] = MFMA_B16(a, b, acc[nt]);
        }
    }

    if (w > 0) {
        #pragma unroll
        for (int nt=0;nt<4;nt++)
            *(floatx4*)(&red[((w-1)*64 + lane)*16 + nt*4]) = acc[nt];
    }
    __syncthreads();
    if (w == 0) {
        #pragma unroll
        for (int nt=0;nt<4;nt++)
            for (int j=0;j<3;j++)
                acc[nt] += *(const floatx4*)(&red[(j*64 + lane)*16 + nt*4]);
        #pragma unroll
        for (int nt=0;nt<4;nt++) {
            int unit = nt*16 + m;
            float bias = fc_b[unit];
            int fr = kg*4;                    // local frame 0..15
            fbuf[(fr+0)*NF + unit] = fmaxf(acc[nt].x + bias, 0.f);
            fbuf[(fr+1)*NF + unit] = fmaxf(acc[nt].y + bias, 0.f);
            fbuf[(fr+2)*NF + unit] = fmaxf(acc[nt].z + bias, 0.f);
            fbuf[(fr+3)*NF + unit] = fmaxf(acc[nt].w + bias, 0.f);
        }
    }
    __syncthreads();

    // xg phase: thread g computes 16 frames x 1 gate
    {
        const int g = tid;
        float a[16];
        float bs = bsum[g];
        #pragma unroll
        for (int i=0;i<16;i++) a[i] = bs;
        for (int k=0;k<64;k++) {
            float wk = wihT[k*256 + g];
            #pragma unroll
            for (int i=0;i<16;i++) a[i] += fbuf[i*64 + k] * wk;
        }
        float* xo = xg + (size_t)(bm*16)*256 + g;
        #pragma unroll
        for (int i=0;i<16;i++) xo[i*256] = a[i];
    }
}

// ================= LSTM recurrence =================
// fast sigmoid/tanh: __expf + hw rcp; saturate correctly at +/-inf
// (validated R10/R11: absmax unchanged at 2.441e-4)
__device__ __forceinline__ float sigmf_(float v){
    return __builtin_amdgcn_rcpf(1.f + __expf(-v));
}
__device__ __forceinline__ float tanhf_(float v){
    return 1.f - 2.f*__builtin_amdgcn_rcpf(__expf(2.f*v) + 1.f);
}

__global__ __launch_bounds__(128) void lstm_kernel(
    const float* __restrict__ xg, const float* __restrict__ whh,
    float* __restrict__ hout)
{
    __shared__ alignas(16) float hbuf[64];
    __shared__ alignas(16) float gbuf[256];
    const int t = threadIdx.x;
    const int b = blockIdx.x;

    float4 w0v[16], w1v[16];
    #pragma unroll
    for (int k=0;k<16;k++) w0v[k] = *(const float4*)(whh + t*64 + k*4);
    #pragma unroll
    for (int k=0;k<16;k++) w1v[k] = *(const float4*)(whh + (t+128)*64 + k*4);

    float c = 0.f;
    if (t < 64) hbuf[t] = 0.f;
    __syncthreads();

    const float* xr = xg + (size_t)(b*128)*256;
    float nA = xr[t];
    float nB = xr[t+128];

    for (int ts=0; ts<128; ++ts) {
        float aA = nA, aB = nB;
        if (ts + 1 < 128) {
            const float* xn = xr + (ts+1)*256;
            nA = xn[t];
            nB = xn[t+128];
        }
        #pragma unroll
        for (int k=0;k<16;k++) {
            float4 hv = *(const float4*)(&hbuf[k*4]);
            aA += hv.x*w0v[k].x + hv.y*w0v[k].y + hv.z*w0v[k].z + hv.w*w0v[k].w;
            aB += hv.x*w1v[k].x + hv.y*w1v[k].y + hv.z*w1v[k].z + hv.w*w1v[k].w;
        }
        gbuf[t] = aA;
        gbuf[t+128] = aB;
        __syncthreads();
        if (t < 64) {   // gate order i,f,g,o
            float ig = sigmf_(gbuf[t]);
            float fg = sigmf_(gbuf[64+t]);
            float gg = tanhf_(gbuf[128+t]);
            float og = sigmf_(gbuf[192+t]);
            c = fg*c + ig*gg;
            float h = og*tanhf_(c);
            hbuf[t] = h;
            hout[(b*128+ts)*64 + t] = h;
        }
        __syncthreads();
    }
}

// ================= policy/value heads (fp32) =================
__global__ __launch_bounds__(64) void heads_kernel(
    const float* __restrict__ hout,
    const float* __restrict__ p1w, const float* __restrict__ p1b,
    const float* __restrict__ p2w, const float* __restrict__ p2b,
    const float* __restrict__ v1w, const float* __restrict__ v1b,
    const float* __restrict__ v2w, const float* __restrict__ v2b,
    float* __restrict__ out)
{
    __shared__ alignas(16) float hbuf[64];
    __shared__ alignas(16) float a1[128];
    __shared__ alignas(16) float a2[128];
    const int lane = threadIdx.x;
    for (int fi=0; fi<4; ++fi) {
        const int f = blockIdx.x*4 + fi;
        hbuf[lane] = hout[f*64 + lane];
        __syncthreads();
        #pragma unroll
        for (int uu=0; uu<2; ++uu) {
            const int u = lane + uu*64;
            float s1 = p1b[u], s2 = v1b[u];
            const float4* wp1 = (const float4*)(p1w + u*64);
            const float4* wv1 = (const float4*)(v1w + u*64);
            #pragma unroll
            for (int k=0;k<16;k++) {
                float4 h4 = *(const float4*)(&hbuf[k*4]);
                float4 w4 = wp1[k];
                s1 += h4.x*w4.x + h4.y*w4.y + h4.z*w4.z + h4.w*w4.w;
                float4 q4 = wv1[k];
                s2 += h4.x*q4.x + h4.y*q4.y + h4.z*q4.z + h4.w*q4.w;
            }
            a1[u] = fmaxf(s1, 0.f);
            a2[u] = fmaxf(s2, 0.f);
        }
        __syncthreads();
        if (lane < 6) {
            float s = p2b[lane];
            const float* wr = p2w + lane*128;
            #pragma unroll
            for (int j=0;j<128;j++) s += a1[j]*wr[j];
            out[f*6 + lane] = s;
        }
        if (lane == 6) {
            float s = v2b[0];
            #pragma unroll
            for (int j=0;j<128;j++) s += a2[j]*v2w[j];
            out[24576 + f] = s;
        }
        __syncthreads();
    }
}

extern "C" void kernel_launch(void* const* d_in, const int* in_sizes, int n_in,
                              void* d_out, int out_size, void* d_ws, size_t ws_size,
                              hipStream_t stream) {
    const float* x       = (const float*)d_in[0];
    const float* conv0_w = (const float*)d_in[1];
    const float* conv0_b = (const float*)d_in[2];
    const float* conv_ws = (const float*)d_in[3];
    const float* conv_bs = (const float*)d_in[4];
    const float* fc_w    = (const float*)d_in[5];
    const float* fc_b    = (const float*)d_in[6];
    const float* w_ih    = (const float*)d_in[7];
    const float* w_hh    = (const float*)d_in[8];
    const float* b_ih    = (const float*)d_in[9];
    const float* b_hh    = (const float*)d_in[10];
    const float* p1_w    = (const float*)d_in[11];
    const float* p1_b    = (const float*)d_in[12];
    const float* p2_w    = (const float*)d_in[13];
    const float* p2_b    = (const float*)d_in[14];
    const float* v1_w    = (const float*)d_in[15];
    const float* v1_b    = (const float*)d_in[16];
    const float* v2_w    = (const float*)d_in[17];
    const float* v2_b    = (const float*)d_in[18];
    float* out = (float*)d_out;

    char* ws = (char*)d_ws;
    short* w0    = (short*)(ws + OFF_W0);
    short* wpk   = (short*)(ws + OFF_WP);
    short* fcp   = (short*)(ws + OFF_FCP);
    float* wihT  = (float*)(ws + OFF_WIHT);
    float* bsum  = (float*)(ws + OFF_BSUM);
    short* acts  = (short*)(ws + OFF_ACTS);
    float* xgb   = (float*)(ws + OFF_XG);
    float* hout  = (float*)(ws + OFF_HOUT);

    prep_kernel<<<1109, 256, 0, stream>>>(conv0_w, conv_ws, w_ih, b_ih, b_hh,
                                          w0, wpk, wihT, bsum);
    fc_transpose<<<64, 256, 0, stream>>>(fc_w, fcp);
    conv_stack<<<N_FRAMES, 128, 0, stream>>>(x, conv0_b, conv_bs, w0, wpk, acts);
    fc_xg_kernel<<<256, 256, 0, stream>>>(acts, fcp, fc_b, wihT, bsum, xgb);
    lstm_kernel<<<32, 128, 0, stream>>>(xgb, w_hh, hout);
    heads_kernel<<<1024, 64, 0, stream>>>(hout, p1_w, p1_b, p2_w, p2_b,
                                          v1_w, v1_b, v2_w, v2_b, out);
}